// Round 1
// 1314.119 us; speedup vs baseline: 1.1327x; 1.1327x over previous
//
#include <hip/hip_runtime.h>

// LSTM_27152783245909 — persistent-recurrence LSTM for MI355X (gfx950)
// R4: flagless tagged-data exchange. h ∈ (-1,1) guarantees bf16 bit14==0 for
// every legit value, so bit14 carries an in-band step-phase tag ((t>>1)&1).
// Consumers poll their own h granules (sc0/sc1) until all shorts show the
// expected tag -- the detecting load IS the data load. Removes per step:
// producer vmcnt(0) drain, flag publish RT, flag-poll RT, and one barrier
// (3.5 coherent round trips -> ~2). h_{-1} is read from the fp32 h0 input
// directly at t=0 (h0 is N(0,1), unbounded, so it must bypass the tag path).
// Buffers memset to 0xFF at launch (bit14=1 != first expected tag 0).

#define T_ 256

typedef __attribute__((ext_vector_type(8))) short bf16x8;
typedef __attribute__((ext_vector_type(4))) float floatx4;
typedef __attribute__((ext_vector_type(4))) int intx4;

__device__ __forceinline__ unsigned short f2bf(float f) {
  unsigned u = __builtin_bit_cast(unsigned, f);
  u += 0x7FFFu + ((u >> 16) & 1u);   // round-nearest-even
  return (unsigned short)(u >> 16);
}

__device__ __forceinline__ float sigm(float x) { return 1.0f / (1.0f + __expf(-x)); }

// ---------------- W_out fp32 -> bf16 (512x1024) ----------------
__global__ void cvt_w(const float* __restrict__ w, unsigned short* __restrict__ o) {
  const size_t g = (size_t)blockIdx.x * 256 + threadIdx.x;
  const float* s = w + g * 8;
  bf16x8 v;
#pragma unroll
  for (int i = 0; i < 8; ++i) v[i] = (short)f2bf(s[i]);
  *(bf16x8*)(o + g * 8) = v;
}

// ---------------- x[B=64, I=512, T=256] fp32 -> xT[T,B,I] bf16 ----------------
__global__ void transpose_x(const float* __restrict__ x, unsigned short* __restrict__ xT) {
  __shared__ float tile[32][33];
  const int b = blockIdx.z, i0 = blockIdx.y * 32, t0 = blockIdx.x * 32;
  const int tx = threadIdx.x & 31, ty = threadIdx.x >> 5;
#pragma unroll
  for (int p = 0; p < 4; ++p) {
    const int i = ty + p * 8;
    tile[i][tx] = x[((size_t)b * 512 + i0 + i) * 256 + t0 + tx];
  }
  __syncthreads();
#pragma unroll
  for (int p = 0; p < 4; ++p) {
    const int t = ty + p * 8;
    xT[((size_t)(t0 + t) * 64 + b) * 512 + i0 + tx] = f2bf(tile[tx][t]);
  }
}

// ---------------- persistent recurrence ----------------
// 256 blocks x 512 thr, 1 block/CU. Block (mg,ng): batch rows [16mg,16mg+16),
// hidden units [16ng,16ng+16). Wave (nh = gate pair, kq = K quarter of 1536).
// Weights in VGPRs (96/lane), c in thread registers. Cross-block h exchange:
// bit14-tagged bf16 shorts via sc0/sc1 (MALL); no flags, no fences.
__global__ __launch_bounds__(512, 1) void lstm_rec(
    const float* __restrict__ Whh, const float* __restrict__ Wih,
    const float* __restrict__ bih, const float* __restrict__ bhh,
    const float* __restrict__ h0, const float* __restrict__ c0,
    const unsigned short* __restrict__ xT,
    unsigned short* __restrict__ hbuf,   // [2][64][1024] bf16 (coherent access only)
    unsigned short* __restrict__ call)   // [256][64][1024] bf16 (normal cached)
{
  const int tid = threadIdx.x;
  const int lane = tid & 63;
  const int wv = tid >> 6;           // 0..7
  const int nh = wv & 1, kq = wv >> 1;
  const int mg = blockIdx.x & 3, ng = blockIdx.x >> 2;
  const int l15 = lane & 15, lq = lane >> 4;
  const int row = mg * 16 + l15;     // A-fragment batch row (x-part)

  __shared__ unsigned short hlds[16 * 1032];      // 16 rows, stride 1032 (+8 pad)
  __shared__ float gpart[4][16][66];              // [kq][m][gate*16+j]

  // persistent B fragments: 2 gates x 12 ksteps = 96 VGPRs/lane
  bf16x8 bfrag[2][12];
#pragma unroll
  for (int nt = 0; nt < 2; ++nt) {
    const int ncol = (2 * nh + nt) * 1024 + ng * 16 + l15;
#pragma unroll
    for (int ks = 0; ks < 12; ++ks) {
      const int kg = kq * 384 + ks * 32 + lq * 8;   // never straddles 1024
      const float* s = (kg < 1024) ? (Whh + (size_t)ncol * 1024 + kg)
                                   : (Wih + (size_t)ncol * 512 + (kg - 1024));
      bf16x8 v;
#pragma unroll
      for (int i = 0; i < 8; ++i) v[i] = (short)f2bf(s[i]);
      bfrag[nt][ks] = v;
    }
  }

  // per-thread state (waves 0..3): one (batch m, unit j) cell each
  const int m_loc = tid >> 4, j = tid & 15;
  const int row_g = mg * 16 + m_loc;
  const int unit = ng * 16 + j;
  float c_reg = 0.f, bs0 = 0.f, bs1 = 0.f, bs2 = 0.f, bs3 = 0.f;
  if (tid < 256) {
    c_reg = c0[unit];
    bs0 = bih[unit] + bhh[unit];
    bs1 = bih[1024 + unit] + bhh[1024 + unit];
    bs2 = bih[2048 + unit] + bhh[2048 + unit];
    bs3 = bih[3072 + unit] + bhh[3072 + unit];
  }

  for (int t = 0; t < T_; ++t) {
    const unsigned short* bx = xT + ((size_t)t * 64 + row) * 512;
    floatx4 zero = {0.f, 0.f, 0.f, 0.f};
    floatx4 acc0 = zero, acc1 = zero;

    // ---- x-part (no dependence on h_{t-1}; overlaps peers' h stores) ----
#pragma unroll
    for (int ks = 0; ks < 12; ++ks) {
      const int kg = kq * 384 + ks * 32 + lq * 8;
      if (kg >= 1024) {
        const bf16x8 af = *(const bf16x8*)(bx + (kg - 1024));
        acc0 = __builtin_amdgcn_mfma_f32_16x16x32_bf16(af, bfrag[0][ks], acc0, 0, 0, 0);
        acc1 = __builtin_amdgcn_mfma_f32_16x16x32_bf16(af, bfrag[1][ks], acc1, 0, 0, 0);
      }
    }

    // ---- obtain h_{t-1} rows [16mg,16mg+16) -> LDS ----
    if (t == 0) {
      // h_{-1} = h0 broadcast over batch; read fp32 input directly (h0 is
      // N(0,1) and may exceed |2| -- must not pass through the tag path).
#pragma unroll
      for (int p = 0; p < 4; ++p) {
        const int e = tid + p * 512;
        const int r = e >> 7, col = (e & 127) * 8;
        const float* s = h0 + col;
        bf16x8 v;
#pragma unroll
        for (int i = 0; i < 8; ++i) v[i] = (short)f2bf(s[i]);
        *(bf16x8*)(hlds + r * 1032 + col) = v;
      }
    } else {
      // tagged poll: load own 64B until every short carries the expected tag.
      // writer of h_{t-1} used tag ((t-1)>>1)&1 in bit14 of each short.
      const unsigned short* hprev = hbuf + ((t + 1) & 1) * 65536;
      const unsigned short* gsrc = hprev + (size_t)(mg * 16) * 1024 + (size_t)tid * 8;
      const unsigned tagpat = (((t - 1) >> 1) & 1) ? 0x40004000u : 0u;
      intx4 a0, a1, a2, a3;
      while (true) {
        asm volatile(
            "global_load_dwordx4 %0, %4, off sc0 sc1\n\t"
            "global_load_dwordx4 %1, %5, off sc0 sc1\n\t"
            "global_load_dwordx4 %2, %6, off sc0 sc1\n\t"
            "global_load_dwordx4 %3, %7, off sc0 sc1\n\t"
            "s_waitcnt vmcnt(0)"
            : "=v"(a0), "=v"(a1), "=v"(a2), "=v"(a3)
            : "v"(gsrc), "v"(gsrc + 4096), "v"(gsrc + 8192), "v"(gsrc + 12288)
            : "memory");
        unsigned bad = 0;
#pragma unroll
        for (int d = 0; d < 4; ++d) {
          bad |= ((unsigned)a0[d] ^ tagpat) & 0x40004000u;
          bad |= ((unsigned)a1[d] ^ tagpat) & 0x40004000u;
          bad |= ((unsigned)a2[d] ^ tagpat) & 0x40004000u;
          bad |= ((unsigned)a3[d] ^ tagpat) & 0x40004000u;
        }
        if (!bad) break;
      }
      intx4 av[4] = {a0, a1, a2, a3};
#pragma unroll
      for (int p = 0; p < 4; ++p) {
        intx4 v = av[p];
#pragma unroll
        for (int d = 0; d < 4; ++d) v[d] &= (int)0xBFFFBFFFu;   // strip tag bit
        const int e = tid + p * 512;
        const int r = e >> 7, col = (e & 127) * 8;
        *(intx4*)(hlds + r * 1032 + col) = v;
      }
    }
    __syncthreads();

    // ---- h-part MFMAs from LDS ----
#pragma unroll
    for (int ks = 0; ks < 12; ++ks) {
      const int kg = kq * 384 + ks * 32 + lq * 8;
      if (kg < 1024) {
        const bf16x8 af = *(const bf16x8*)(hlds + l15 * 1032 + kg);
        acc0 = __builtin_amdgcn_mfma_f32_16x16x32_bf16(af, bfrag[0][ks], acc0, 0, 0, 0);
        acc1 = __builtin_amdgcn_mfma_f32_16x16x32_bf16(af, bfrag[1][ks], acc1, 0, 0, 0);
      }
    }

    // C layout: col = lane&15, row = (lane>>4)*4 + r
#pragma unroll
    for (int r = 0; r < 4; ++r) {
      gpart[kq][lq * 4 + r][(2 * nh) * 16 + l15]     = acc0[r];
      gpart[kq][lq * 4 + r][(2 * nh + 1) * 16 + l15] = acc1[r];
    }
    __syncthreads();

    if (tid < 256) {
      float gi = bs0, gf = bs1, gg = bs2, go = bs3;
#pragma unroll
      for (int q = 0; q < 4; ++q) {
        gi += gpart[q][m_loc][j];
        gf += gpart[q][m_loc][16 + j];
        gg += gpart[q][m_loc][32 + j];
        go += gpart[q][m_loc][48 + j];
      }
      const float iv = sigm(gi), fv = sigm(gf), gv = tanhf(gg), ov = sigm(go);
      c_reg = fv * c_reg + iv * gv;
      const float hv = ov * tanhf(c_reg);
      call[((size_t)t * 64 + row_g) * 1024 + unit] = f2bf(c_reg);
      // publish h with bit14 tag; |hv| < 1 so bit14 of f2bf(hv) is always 0.
      unsigned short* hp = hbuf + (t & 1) * 65536 + row_g * 1024 + unit;
      const unsigned hb = (unsigned)f2bf(hv) | ((unsigned)((t >> 1) & 1) << 14);
      asm volatile("global_store_short %0, %1, off sc0 sc1"
                   :: "v"(hp), "v"(hb) : "memory");
      // no vmcnt drain, no flag, no trailing barrier -- consumers poll the
      // tagged data itself.
    }
    // 2 barriers/step: next iteration's hlds write is safe (everyone passed
    // the gpart barrier, which post-dates all hlds reads), and gpart reads by
    // tid<256 complete before those threads reach the next hlds barrier.
  }
}

// ---------------- output head: logits + softmax, fully parallel over t ----------------
__global__ __launch_bounds__(256, 1) void lstm_head(
    const unsigned short* __restrict__ call,
    const unsigned short* __restrict__ wout,
    const float* __restrict__ bout,
    float* __restrict__ out)
{
  const int tb = blockIdx.x;
  const int lane = threadIdx.x & 63;
  const int wv = threadIdx.x >> 6;
  const int l15 = lane & 15, lq = lane >> 4;

  __shared__ float sred[2][4][64];

  floatx4 zero = {0.f, 0.f, 0.f, 0.f};
  floatx4 acc[4][8];
#pragma unroll
  for (int mt = 0; mt < 4; ++mt)
#pragma unroll
    for (int nt = 0; nt < 8; ++nt) acc[mt][nt] = zero;

  const unsigned short* abase = call + ((size_t)tb * 64 + l15) * 1024 + lq * 8;
  const unsigned short* bbase = wout + ((size_t)(wv * 128 + l15)) * 1024 + lq * 8;

#pragma unroll 2
  for (int ks = 0; ks < 32; ++ks) {
    bf16x8 a[4];
#pragma unroll
    for (int mt = 0; mt < 4; ++mt)
      a[mt] = *(const bf16x8*)(abase + (size_t)mt * 16 * 1024 + ks * 32);
#pragma unroll
    for (int nt = 0; nt < 8; ++nt) {
      const bf16x8 b = *(const bf16x8*)(bbase + (size_t)nt * 16 * 1024 + ks * 32);
#pragma unroll
      for (int mt = 0; mt < 4; ++mt)
        acc[mt][nt] = __builtin_amdgcn_mfma_f32_16x16x32_bf16(a[mt], b, acc[mt][nt], 0, 0, 0);
    }
  }

#pragma unroll
  for (int nt = 0; nt < 8; ++nt) {
    const float bo = bout[wv * 128 + nt * 16 + l15];
#pragma unroll
    for (int mt = 0; mt < 4; ++mt)
#pragma unroll
      for (int r = 0; r < 4; ++r) acc[mt][nt][r] += bo;
  }

  float rmax[4][4];
#pragma unroll
  for (int mt = 0; mt < 4; ++mt)
#pragma unroll
    for (int r = 0; r < 4; ++r) {
      float m = acc[mt][0][r];
#pragma unroll
      for (int nt = 1; nt < 8; ++nt) m = fmaxf(m, acc[mt][nt][r]);
      m = fmaxf(m, __shfl_xor(m, 1, 64));
      m = fmaxf(m, __shfl_xor(m, 2, 64));
      m = fmaxf(m, __shfl_xor(m, 4, 64));
      m = fmaxf(m, __shfl_xor(m, 8, 64));
      rmax[mt][r] = m;
    }
  if (l15 == 0) {
#pragma unroll
    for (int mt = 0; mt < 4; ++mt)
#pragma unroll
      for (int r = 0; r < 4; ++r) sred[0][wv][mt * 16 + lq * 4 + r] = rmax[mt][r];
  }
  __syncthreads();
  float gmax[4][4], rsum[4][4];
#pragma unroll
  for (int mt = 0; mt < 4; ++mt)
#pragma unroll
    for (int r = 0; r < 4; ++r) {
      const int rw = mt * 16 + lq * 4 + r;
      gmax[mt][r] = fmaxf(fmaxf(sred[0][0][rw], sred[0][1][rw]),
                          fmaxf(sred[0][2][rw], sred[0][3][rw]));
      rsum[mt][r] = 0.f;
    }
#pragma unroll
  for (int mt = 0; mt < 4; ++mt)
#pragma unroll
    for (int nt = 0; nt < 8; ++nt)
#pragma unroll
      for (int r = 0; r < 4; ++r) {
        const float e = __expf(acc[mt][nt][r] - gmax[mt][r]);
        acc[mt][nt][r] = e;
        rsum[mt][r] += e;
      }
#pragma unroll
  for (int mt = 0; mt < 4; ++mt)
#pragma unroll
    for (int r = 0; r < 4; ++r) {
      float s = rsum[mt][r];
      s += __shfl_xor(s, 1, 64);
      s += __shfl_xor(s, 2, 64);
      s += __shfl_xor(s, 4, 64);
      s += __shfl_xor(s, 8, 64);
      rsum[mt][r] = s;
    }
  if (l15 == 0) {
#pragma unroll
    for (int mt = 0; mt < 4; ++mt)
#pragma unroll
      for (int r = 0; r < 4; ++r) sred[1][wv][mt * 16 + lq * 4 + r] = rsum[mt][r];
  }
  __syncthreads();
#pragma unroll
  for (int mt = 0; mt < 4; ++mt)
#pragma unroll
    for (int r = 0; r < 4; ++r) {
      const int rw = mt * 16 + lq * 4 + r;
      const float inv = 1.0f / (sred[1][0][rw] + sred[1][1][rw] +
                                sred[1][2][rw] + sred[1][3][rw]);
      float* orow = out + ((size_t)tb * 64 + rw) * 512 + wv * 128 + l15;
#pragma unroll
      for (int nt = 0; nt < 8; ++nt) orow[nt * 16] = acc[mt][nt][r] * inv;
    }
}

// ---------------- launch ----------------
extern "C" void kernel_launch(void* const* d_in, const int* in_sizes, int n_in,
                              void* d_out, int out_size, void* d_ws, size_t ws_size,
                              hipStream_t stream) {
  const float* x    = (const float*)d_in[0];
  const float* Wih  = (const float*)d_in[1];
  const float* Whh  = (const float*)d_in[2];
  const float* bih  = (const float*)d_in[3];
  const float* bhh  = (const float*)d_in[4];
  const float* Wout = (const float*)d_in[5];
  const float* bout = (const float*)d_in[6];
  const float* h0   = (const float*)d_in[7];
  const float* c0   = (const float*)d_in[8];
  float* out = (float*)d_out;

  char* ws = (char*)d_ws;
  unsigned short* hbuf  = (unsigned short*)(ws + 4096);         //   256 KB
  unsigned short* woutb = (unsigned short*)(ws + 266240);       //     1 MB
  unsigned short* xT    = (unsigned short*)(ws + 1314816);      //    16 MB
  unsigned short* call  = (unsigned short*)(ws + 18092032);     //    32 MB

  // poison both h buffers: 0xFFFF has bit14=1, first expected tag is 0 for
  // both buffers (buf0 first polled at t=1 for tag0; buf1 at t=2 for tag0).
  hipMemsetAsync(hbuf, 0xFF, 262144, stream);
  cvt_w<<<256, 256, 0, stream>>>(Wout, woutb);
  transpose_x<<<dim3(8, 16, 64), 256, 0, stream>>>(x, xT);
  lstm_rec<<<256, 512, 0, stream>>>(Whh, Wih, bih, bhh, h0, c0, xT, hbuf, call);
  lstm_head<<<256, 256, 0, stream>>>(call, woutb, bout, out);
}